// Round 3
// baseline (247.119 us; speedup 1.0000x reference)
//
#include <hip/hip_runtime.h>
#include <cstdint>
#include <cstddef>

typedef __attribute__((ext_vector_type(8))) __bf16 bf16x8;
typedef __attribute__((ext_vector_type(4))) float f32x4;

#define MFMA16(a, b, c) __builtin_amdgcn_mfma_f32_16x16x32_bf16((a), (b), (c), 0, 0, 0)
#define BPERM(i, s) __builtin_amdgcn_ds_bpermute((i), (s))

__device__ __forceinline__ float fast_tanh(float z) {
    float e = __expf(2.0f * z);
    return 1.0f - 2.0f * __builtin_amdgcn_rcpf(e + 1.0f);
}
__device__ __forceinline__ float fast_sigmoid(float z) {
    return __builtin_amdgcn_rcpf(1.0f + __expf(-z));
}

__device__ __forceinline__ int pk2(float a, float b) {
    union { __bf16 h[2]; int u; } p;
    p.h[0] = (__bf16)a;
    p.h[1] = (__bf16)b;
    return p.u;
}

__device__ __forceinline__ bf16x8 frag4(int a, int b, int c, int d) {
    union { int w[4]; bf16x8 f; } u;
    u.w[0] = a; u.w[1] = b; u.w[2] = c; u.w[3] = d;
    return u.f;
}

__device__ __forceinline__ bf16x8 cvt8(float4 a, float4 b) {
    bf16x8 f;
    f[0] = (__bf16)a.x; f[1] = (__bf16)a.y; f[2] = (__bf16)a.z; f[3] = (__bf16)a.w;
    f[4] = (__bf16)b.x; f[5] = (__bf16)b.y; f[6] = (__bf16)b.z; f[7] = (__bf16)b.w;
    return f;
}

// weight A-fragment: lane holds row `row`, k = k0..k0+7 (row-major W[64][64])
__device__ __forceinline__ bf16x8 ldwfrag(const float* __restrict__ W, int row, int k0) {
    const float4 a = *(const float4*)(W + row * 64 + k0);
    const float4 b = *(const float4*)(W + row * 64 + k0 + 4);
    bf16x8 f;
    f[0] = (__bf16)a.x; f[1] = (__bf16)a.y; f[2] = (__bf16)a.z; f[3] = (__bf16)a.w;
    f[4] = (__bf16)b.x; f[5] = (__bf16)b.y; f[6] = (__bf16)b.z; f[7] = (__bf16)b.w;
    return f;
}

// per-lane select of the owned row-tile's accumulator (rt_own = sc>>2)
__device__ __forceinline__ f32x4 sel4(f32x4 a0, f32x4 a1, f32x4 a2, f32x4 a3, int sc) {
    f32x4 r;
#pragma unroll
    for (int i = 0; i < 4; ++i) {
        float lo = (sc & 4) ? a1[i] : a0[i];
        float hi = (sc & 4) ? a3[i] : a2[i];
        r[i] = (sc & 8) ? hi : lo;
    }
    return r;
}

// Cox-de Boor, order 3, 12 knots -> 8 basis funcs (exact reference replication).
__device__ __forceinline__ void bspl8(float x, const float* kn, float* B) {
    float b[11];
#pragma unroll
    for (int m = 0; m < 11; ++m)
        b[m] = (x >= kn[m] && x < kn[m + 1]) ? 1.0f : 0.0f;
#pragma unroll
    for (int d = 1; d <= 3; ++d) {
#pragma unroll
        for (int m = 0; m + d < 11; ++m) {
            float lf = (x - kn[m]) / (kn[m + d] - kn[m]) * b[m];
            float rt = (kn[m + d + 1] - x) / (kn[m + d + 1] - kn[m + 1]) * b[m + 1];
            b[m] = lf + rt;
        }
    }
#pragma unroll
    for (int m = 0; m < 8; ++m) B[m] = b[m];
}

// One WAVE (64 threads) per 4 samples. Wave owns all 64 hidden rows; B-operand
// columns replicated (col sc carries sample sc&3). No LDS / no barriers in the
// recurrence: C->B exchange via in-wave ds_bpermute. Layer-skewed (iter t
// computes h1[t] and h2[t-1]). x loaded direct-to-VGPR 2 steps ahead.
__global__ __launch_bounds__(64, 1) void rnn_kan_wave(
    const float* __restrict__ x,
    const float* __restrict__ wih0, const float* __restrict__ whh0,
    const float* __restrict__ bih0, const float* __restrict__ bhh0,
    const float* __restrict__ wih1, const float* __restrict__ whh1,
    const float* __restrict__ bih1, const float* __restrict__ bhh1,
    const float* __restrict__ grid0, const float* __restrict__ coef0,
    const float* __restrict__ sb0, const float* __restrict__ sp0,
    const float* __restrict__ grid1, const float* __restrict__ coef1,
    const float* __restrict__ sb1, const float* __restrict__ sp1,
    float* __restrict__ out)
{
    __shared__ __align__(16) float s_hf[4][68];    // final h2 fp32
    __shared__ __align__(16) float s_bas[256][12]; // KAN0 basis[8] + silu at [8]
    __shared__ __align__(16) float s_e[4][17];     // KAN1 edge values

    const int lane  = threadIdx.x;
    const int sc    = lane & 15;   // MFMA col (replicated sample slot)
    const int gr    = lane >> 4;   // 16-lane group
    const int samp  = sc & 3;      // sample this col carries
    const int rt_own = sc >> 2;    // row-tile this lane tanh's
    const int s0    = blockIdx.x << 2;

    // ---- weights -> A-fragments: frag[rt][kt], row = 16rt+sc, k = 32kt+8gr..+7
    bf16x8 fWih0[4][2], fWhh0[4][2], fWih1[4][2], fWhh1[4][2];
#pragma unroll
    for (int rt = 0; rt < 4; ++rt)
#pragma unroll
        for (int kt = 0; kt < 2; ++kt) {
            fWih0[rt][kt] = ldwfrag(wih0, 16 * rt + sc, 32 * kt + 8 * gr);
            fWhh0[rt][kt] = ldwfrag(whh0, 16 * rt + sc, 32 * kt + 8 * gr);
            fWih1[rt][kt] = ldwfrag(wih1, 16 * rt + sc, 32 * kt + 8 * gr);
            fWhh1[rt][kt] = ldwfrag(whh1, 16 * rt + sc, 32 * kt + 8 * gr);
        }

    // biases for OWNED rows only: R = 16*rt_own + 4*gr + i
    f32x4 bo0, bo1, zero;
#pragma unroll
    for (int i = 0; i < 4; ++i) {
        const int R = 16 * rt_own + 4 * gr + i;
        bo0[i] = bih0[R] + bhh0[R];
        bo1[i] = bih1[R] + bhh1[R];
        zero[i] = 0.0f;
    }

    // ---- bpermute byte-indices: dest word w (kt=w>>2, w'=w&3) -> pair m,
    // source lane 4*(m>>3) + samp + 16*((m>>1)&3); parity m&1 picks W0/W1.
    int pidx[8];
#pragma unroll
    for (int w = 0; w < 8; ++w) {
        const int m = 16 * (w >> 2) + 4 * gr + (w & 3);
        pidx[w] = 4 * (4 * (m >> 3) + samp + 16 * ((m >> 1) & 3));
    }

    // ---- x pipeline: lane loads sample `samp`, k = 8gr..+7 (+32 for kt1)
    const float* xb = x + (size_t)(s0 + samp) * 16384 + 8 * gr;
    float4 r0, r1, r2, r3;
    r0 = *(const float4*)(xb);      r1 = *(const float4*)(xb + 4);
    r2 = *(const float4*)(xb + 32); r3 = *(const float4*)(xb + 36);
    bf16x8 xf0 = cvt8(r0, r1), xf1 = cvt8(r2, r3);      // x(0)
    r0 = *(const float4*)(xb + 64);      r1 = *(const float4*)(xb + 68);
    r2 = *(const float4*)(xb + 96);      r3 = *(const float4*)(xb + 100);  // x(1)

    bf16x8 h1B0, h1B1, h2B0, h2B1;
    {
        bf16x8 zf;
#pragma unroll
        for (int e = 0; e < 8; ++e) zf[e] = (__bf16)0.0f;
        h1B0 = zf; h1B1 = zf; h2B0 = zf; h2B1 = zf;
    }

    // ---- recurrence: no LDS, no barriers
    for (int t = 0; t < 256; ++t) {
        bf16x8 xn0 = cvt8(r0, r1), xn1 = cvt8(r2, r3);  // x(t+1)
        {
            const float* pn = xb + (size_t)((t + 2 > 255) ? 255 : t + 2) * 64;
            r0 = *(const float4*)(pn);      r1 = *(const float4*)(pn + 4);
            r2 = *(const float4*)(pn + 32); r3 = *(const float4*)(pn + 36);
        }

        // z1 = b0 + Wih0@x(t) + Whh0@h1(t-1); z2 = b1 + Wih1@h1(t-1) + Whh1@h2(t-2)
        f32x4 a[4], c[4];
#pragma unroll
        for (int rt = 0; rt < 4; ++rt) {
            f32x4 t1 = MFMA16(fWih0[rt][0], xf0, zero);
            t1 = MFMA16(fWih0[rt][1], xf1, t1);
            t1 = MFMA16(fWhh0[rt][0], h1B0, t1);
            a[rt] = MFMA16(fWhh0[rt][1], h1B1, t1);
            f32x4 t2 = MFMA16(fWih1[rt][0], h1B0, zero);
            t2 = MFMA16(fWih1[rt][1], h1B1, t2);
            t2 = MFMA16(fWhh1[rt][0], h2B0, t2);
            c[rt] = MFMA16(fWhh1[rt][1], h2B1, t2);
        }

        // h1(t): select owned rows, bias, tanh, pack, bpermute to B-frags
        f32x4 oz = sel4(a[0], a[1], a[2], a[3], sc) + bo0;
        float v[4];
#pragma unroll
        for (int i = 0; i < 4; ++i) v[i] = fast_tanh(oz[i]);
        const int W0 = pk2(v[0], v[1]), W1 = pk2(v[2], v[3]);
        h1B0 = frag4(BPERM(pidx[0], W0), BPERM(pidx[1], W1),
                     BPERM(pidx[2], W0), BPERM(pidx[3], W1));
        h1B1 = frag4(BPERM(pidx[4], W0), BPERM(pidx[5], W1),
                     BPERM(pidx[6], W0), BPERM(pidx[7], W1));

        // h2(t-1): same path (discard at t=0 so h2B stays h2(-1)=0)
        f32x4 oz2 = sel4(c[0], c[1], c[2], c[3], sc) + bo1;
        float u[4];
#pragma unroll
        for (int i = 0; i < 4; ++i) u[i] = fast_tanh(oz2[i]);
        const int U0 = pk2(u[0], u[1]), U1 = pk2(u[2], u[3]);
        const bf16x8 nh0 = frag4(BPERM(pidx[0], U0), BPERM(pidx[1], U1),
                                 BPERM(pidx[2], U0), BPERM(pidx[3], U1));
        const bf16x8 nh1 = frag4(BPERM(pidx[4], U0), BPERM(pidx[5], U1),
                                 BPERM(pidx[6], U0), BPERM(pidx[7], U1));
        if (t != 0) { h2B0 = nh0; h2B1 = nh1; }

        xf0 = xn0; xf1 = xn1;
    }

    // ---- final h2(255) = tanh(b1 + Wih1@h1(255) + Whh1@h2(254)) -> LDS
    {
        f32x4 c[4];
#pragma unroll
        for (int rt = 0; rt < 4; ++rt) {
            f32x4 t2 = MFMA16(fWih1[rt][0], h1B0, zero);
            t2 = MFMA16(fWih1[rt][1], h1B1, t2);
            t2 = MFMA16(fWhh1[rt][0], h2B0, t2);
            c[rt] = MFMA16(fWhh1[rt][1], h2B1, t2);
        }
        f32x4 oz2 = sel4(c[0], c[1], c[2], c[3], sc) + bo1;
        f32x4 hv;
#pragma unroll
        for (int i = 0; i < 4; ++i) hv[i] = fast_tanh(oz2[i]);
        *(f32x4*)(&s_hf[samp][16 * rt_own + 4 * gr]) = hv;
    }
    __syncthreads();

    // ---- KAN epilogue (4 samples, 64 lanes)
    float kn0[12], kn1[12];
#pragma unroll
    for (int m = 0; m < 12; ++m) { kn0[m] = grid0[m]; kn1[m] = grid1[m]; }

    // K1: basis + silu for all 256 (i, s) pairs, q = 4*i + s
#pragma unroll
    for (int j = 0; j < 4; ++j) {
        const int q = lane + 64 * j;
        const int i = q >> 2, s = q & 3;
        const float v = s_hf[s][i];
        float B[8];
        bspl8(v, kn0, B);
        *(float4*)(&s_bas[q][0]) = make_float4(B[0], B[1], B[2], B[3]);
        *(float4*)(&s_bas[q][4]) = make_float4(B[4], B[5], B[6], B[7]);
        s_bas[q][8] = v * fast_sigmoid(v);
    }
    __syncthreads();

    // K2: KAN0 out[s][o]; K3: KAN1 edge for (s,o) — one lane per (s,o)
    {
        const int s = lane >> 4, o = lane & 15;
        float acc = 0.0f;
        for (int i = 0; i < 64; ++i) {
            const int q = (i << 2) + s;
            const float4 B0 = *(const float4*)(&s_bas[q][0]);
            const float4 B1 = *(const float4*)(&s_bas[q][4]);
            const float sil = s_bas[q][8];
            const float* cp = coef0 + i * 128 + o * 8;
            const float4 c0 = *(const float4*)cp;
            const float4 c1 = *(const float4*)(cp + 4);
            const float spl = B0.x * c0.x + B0.y * c0.y + B0.z * c0.z + B0.w * c0.w +
                              B1.x * c1.x + B1.y * c1.y + B1.z * c1.z + B1.w * c1.w;
            acc += sil * sb0[(i << 4) + o] + sp0[(i << 4) + o] * spl;
        }
        float B[8];
        bspl8(acc, kn1, B);
        const float* cp = coef1 + o * 8;
        float spl = 0.0f;
#pragma unroll
        for (int k = 0; k < 8; ++k) spl += B[k] * cp[k];
        s_e[s][o] = (acc * fast_sigmoid(acc)) * sb1[o] + sp1[o] * spl;
    }
    __syncthreads();

    // K4: reduce 16 edges per sample, sigmoid, store
    if (lane < 4) {
        float sum = 0.0f;
#pragma unroll
        for (int o = 0; o < 16; ++o) sum += s_e[lane][o];
        out[s0 + lane] = fast_sigmoid(sum);
    }
}

extern "C" void kernel_launch(void* const* d_in, const int* in_sizes, int n_in,
                              void* d_out, int out_size, void* d_ws, size_t ws_size,
                              hipStream_t stream) {
    (void)n_in; (void)out_size; (void)d_ws; (void)ws_size;
    const int B = in_sizes[0] / (256 * 64);   // 2048
    const int grid = B / 4;                   // 512 waves of 4 samples
    rnn_kan_wave<<<dim3(grid), dim3(64), 0, stream>>>(
        (const float*)d_in[0],
        (const float*)d_in[1], (const float*)d_in[2], (const float*)d_in[3], (const float*)d_in[4],
        (const float*)d_in[5], (const float*)d_in[6], (const float*)d_in[7], (const float*)d_in[8],
        (const float*)d_in[9], (const float*)d_in[10], (const float*)d_in[11], (const float*)d_in[12],
        (const float*)d_in[13], (const float*)d_in[14], (const float*)d_in[15], (const float*)d_in[16],
        (float*)d_out);
}

// Round 4
// 165.600 us; speedup vs baseline: 1.4923x; 1.4923x over previous
//
#include <hip/hip_runtime.h>
#include <cstdint>
#include <cstddef>

typedef __attribute__((ext_vector_type(8))) __bf16 bf16x8;
typedef __attribute__((ext_vector_type(4))) float f32x4;

#define MFMA16(a, b, c) __builtin_amdgcn_mfma_f32_16x16x32_bf16((a), (b), (c), 0, 0, 0)

__device__ __forceinline__ float fast_tanh(float z) {
    float e = __expf(2.0f * z);
    return 1.0f - 2.0f * __builtin_amdgcn_rcpf(e + 1.0f);
}
__device__ __forceinline__ float fast_sigmoid(float z) {
    return __builtin_amdgcn_rcpf(1.0f + __expf(-z));
}

__device__ __forceinline__ unsigned pk2(float a, float b) {
    union { __bf16 h[2]; unsigned u; } p;
    p.h[0] = (__bf16)a;
    p.h[1] = (__bf16)b;
    return p.u;
}

__device__ __forceinline__ bf16x8 cvt8(float4 a, float4 b) {
    bf16x8 f;
    f[0] = (__bf16)a.x; f[1] = (__bf16)a.y; f[2] = (__bf16)a.z; f[3] = (__bf16)a.w;
    f[4] = (__bf16)b.x; f[5] = (__bf16)b.y; f[6] = (__bf16)b.z; f[7] = (__bf16)b.w;
    return f;
}

// weight A-fragment: lane holds row `row`, k = k0..k0+7 (row-major W[64][64])
__device__ __forceinline__ bf16x8 ldwfrag(const float* __restrict__ W, int row, int k0) {
    const float4 a = *(const float4*)(W + row * 64 + k0);
    const float4 b = *(const float4*)(W + row * 64 + k0 + 4);
    bf16x8 f;
    f[0] = (__bf16)a.x; f[1] = (__bf16)a.y; f[2] = (__bf16)a.z; f[3] = (__bf16)a.w;
    f[4] = (__bf16)b.x; f[5] = (__bf16)b.y; f[6] = (__bf16)b.z; f[7] = (__bf16)b.w;
    return f;
}

// Cox-de Boor, order 3, 12 knots -> 8 basis funcs (exact reference replication).
__device__ __forceinline__ void bspl8(float x, const float* kn, float* B) {
    float b[11];
#pragma unroll
    for (int m = 0; m < 11; ++m)
        b[m] = (x >= kn[m] && x < kn[m + 1]) ? 1.0f : 0.0f;
#pragma unroll
    for (int d = 1; d <= 3; ++d) {
#pragma unroll
        for (int m = 0; m + d < 11; ++m) {
            float lf = (x - kn[m]) / (kn[m + d] - kn[m]) * b[m];
            float rt = (kn[m + d + 1] - x) / (kn[m + d + 1] - kn[m + 1]) * b[m + 1];
            b[m] = lf + rt;
        }
    }
#pragma unroll
    for (int m = 0; m < 8; ++m) B[m] = b[m];
}

// One block = 16 samples through 256 steps of both RNN layers + KAN.
// 4 waves; wave wv owns hidden rows [16wv,16wv+16). Layer-skewed (iter t makes
// h1[t], h2[t-1]) -> ONE barrier/step. x loaded global->VGPR per-lane (no LDS
// staging); b0+Wih0@x[t+1] and b1+Whh1@h2[t-2] computed in barrier shadows.
__global__ __launch_bounds__(256, 1) void rnn_kan_v4(
    const float* __restrict__ x,
    const float* __restrict__ wih0, const float* __restrict__ whh0,
    const float* __restrict__ bih0, const float* __restrict__ bhh0,
    const float* __restrict__ wih1, const float* __restrict__ whh1,
    const float* __restrict__ bih1, const float* __restrict__ bhh1,
    const float* __restrict__ grid0, const float* __restrict__ coef0,
    const float* __restrict__ sb0, const float* __restrict__ sp0,
    const float* __restrict__ grid1, const float* __restrict__ coef1,
    const float* __restrict__ sb1, const float* __restrict__ sp1,
    float* __restrict__ out)
{
    __shared__ __align__(16) unsigned char s_h1[2][2048]; // h1 bf16, dbuf, swizzled
    __shared__ __align__(16) unsigned char s_h2[2][2048]; // h2 bf16
    __shared__ __align__(16) float s_hf[16][68];          // final h2 fp32
    __shared__ __align__(16) float s_bas[1024][12];       // KAN0 basis[8] + silu at [8]
    __shared__ __align__(16) float s_e[16][17];           // KAN1 edge values

    const int tid  = threadIdx.x;
    const int wv   = tid >> 6;
    const int lane = tid & 63;
    const int sc   = lane & 15;   // MFMA col (= sample)
    const int gr   = lane >> 4;   // 16-lane group
    const int s0   = blockIdx.x << 4;

    // weights -> A-fragments (row = 16wv+sc, k = 32kt+8gr..+7)
    const int wrow = 16 * wv + sc;
    const int kofs = 8 * gr;
    bf16x8 fWih0[2], fWhh0[2], fWih1[2], fWhh1[2];
#pragma unroll
    for (int kt = 0; kt < 2; ++kt) {
        fWih0[kt] = ldwfrag(wih0, wrow, 32 * kt + kofs);
        fWhh0[kt] = ldwfrag(whh0, wrow, 32 * kt + kofs);
        fWih1[kt] = ldwfrag(wih1, wrow, 32 * kt + kofs);
        fWhh1[kt] = ldwfrag(whh1, wrow, 32 * kt + kofs);
    }
    f32x4 b0v, b1v;
#pragma unroll
    for (int i = 0; i < 4; ++i) {
        const int h = 16 * wv + 4 * gr + i;
        b0v[i] = bih0[h] + bhh0[h];
        b1v[i] = bih1[h] + bhh1[h];
    }

    // LDS h-buffer byte offsets (XOR-swizzle on byte bits 4..6)
    const unsigned swz  = (unsigned)(sc & 7) << 4;
    const unsigned offW  = sc * 128 + (((unsigned)(32 * wv + 8 * gr)) ^ swz); // C write (b64)
    const unsigned offR0 = sc * 128 + (((unsigned)(16 * gr)) ^ swz);          // B-frag kt=0 (b128)
    const unsigned offR1 = sc * 128 + (((unsigned)(64 + 16 * gr)) ^ swz);     // B-frag kt=1

    // x gather base: lane reads sample sc, k = 8gr..+7 (+32 for kt1); 64B/step/sample
    const float* xb = x + (size_t)(s0 + sc) * 16384 + kofs;

    // ---- prologue: x[0] -> xz; ra = x[1], rb = x[2] raw
    float4 q0 = *(const float4*)(xb);      float4 q1 = *(const float4*)(xb + 4);
    float4 q2 = *(const float4*)(xb + 32); float4 q3 = *(const float4*)(xb + 36);
    float4 ra0 = *(const float4*)(xb + 64),  ra1 = *(const float4*)(xb + 68);
    float4 ra2 = *(const float4*)(xb + 96),  ra3 = *(const float4*)(xb + 100);
    float4 rb0 = *(const float4*)(xb + 128), rb1 = *(const float4*)(xb + 132);
    float4 rb2 = *(const float4*)(xb + 160), rb3 = *(const float4*)(xb + 164);

    f32x4 xz = MFMA16(fWih0[0], cvt8(q0, q1), b0v);
    xz = MFMA16(fWih0[1], cvt8(q2, q3), xz);

    // ---- peel t=0: h1[0] = tanh(xz)  (h1[-1]=0)
    {
        float v[4];
#pragma unroll
        for (int i = 0; i < 4; ++i) v[i] = fast_tanh(xz[i]);
        uint2 pw; pw.x = pk2(v[0], v[1]); pw.y = pk2(v[2], v[3]);
        *(uint2*)((char*)(&s_h1[0][0]) + offW) = pw;
    }
    // xz for t=1 from ra; shift ring; load x[3]
    xz = MFMA16(fWih0[0], cvt8(ra0, ra1), b0v);
    xz = MFMA16(fWih0[1], cvt8(ra2, ra3), xz);
    ra0 = rb0; ra1 = rb1; ra2 = rb2; ra3 = rb3;
    rb0 = *(const float4*)(xb + 192); rb1 = *(const float4*)(xb + 196);
    rb2 = *(const float4*)(xb + 224); rb3 = *(const float4*)(xb + 228);

    asm volatile("s_waitcnt lgkmcnt(0)" ::: "memory");
    __builtin_amdgcn_s_barrier();
    asm volatile("" ::: "memory");

    bf16x8 h1f0 = *(const bf16x8*)((const char*)(&s_h1[0][0]) + offR0);
    bf16x8 h1f1 = *(const bf16x8*)((const char*)(&s_h1[0][0]) + offR1);
    f32x4 h2z = b1v;   // = b1 + Whh1 @ h2[-1] (zero)

    // ---- main loop t = 1..255
    for (int t = 1; t < 256; ++t) {
        const int par = t & 1;
        // h1[t] preact = xz + Whh0 @ h1[t-1]
        f32x4 z1 = MFMA16(fWhh0[0], h1f0, xz);
        z1 = MFMA16(fWhh0[1], h1f1, z1);
        // h2[t-1] preact = h2z + Wih1 @ h1[t-1]
        f32x4 z2 = MFMA16(fWih1[0], h1f0, h2z);
        z2 = MFMA16(fWih1[1], h1f1, z2);

        float v1[4], v2[4];
#pragma unroll
        for (int i = 0; i < 4; ++i) v1[i] = fast_tanh(z1[i]);
        uint2 pw1; pw1.x = pk2(v1[0], v1[1]); pw1.y = pk2(v1[2], v1[3]);
        *(uint2*)((char*)(&s_h1[par][0]) + offW) = pw1;
#pragma unroll
        for (int i = 0; i < 4; ++i) v2[i] = fast_tanh(z2[i]);
        uint2 pw2; pw2.x = pk2(v2[0], v2[1]); pw2.y = pk2(v2[2], v2[3]);
        *(uint2*)((char*)(&s_h2[par][0]) + offW) = pw2;

        // shadow: xz for t+1; ring shift; prefetch x[t+3]
        xz = MFMA16(fWih0[0], cvt8(ra0, ra1), b0v);
        xz = MFMA16(fWih0[1], cvt8(ra2, ra3), xz);
        ra0 = rb0; ra1 = rb1; ra2 = rb2; ra3 = rb3;
        {
            const float* pn = xb + (size_t)((t + 3 > 255) ? 255 : t + 3) * 64;
            rb0 = *(const float4*)(pn);      rb1 = *(const float4*)(pn + 4);
            rb2 = *(const float4*)(pn + 32); rb3 = *(const float4*)(pn + 36);
        }

        asm volatile("s_waitcnt lgkmcnt(0)" ::: "memory");
        __builtin_amdgcn_s_barrier();
        asm volatile("" ::: "memory");

        // reads: h2 first (feeds h2z immediately), then h1
        bf16x8 h2f0 = *(const bf16x8*)((const char*)(&s_h2[par][0]) + offR0);
        bf16x8 h2f1 = *(const bf16x8*)((const char*)(&s_h2[par][0]) + offR1);
        h1f0 = *(const bf16x8*)((const char*)(&s_h1[par][0]) + offR0);
        h1f1 = *(const bf16x8*)((const char*)(&s_h1[par][0]) + offR1);

        // shadow for next iter: h2z = b1 + Whh1 @ h2[t-1]
        h2z = MFMA16(fWhh1[0], h2f0, b1v);
        h2z = MFMA16(fWhh1[1], h2f1, h2z);
    }

    // ---- final h2[255] = tanh(h2z + Wih1 @ h1[255]) -> fp32 LDS
    {
        f32x4 z2 = MFMA16(fWih1[0], h1f0, h2z);
        z2 = MFMA16(fWih1[1], h1f1, z2);
        f32x4 hv;
#pragma unroll
        for (int i = 0; i < 4; ++i) hv[i] = fast_tanh(z2[i]);
        *(f32x4*)(&s_hf[sc][16 * wv + 4 * gr]) = hv;
    }
    __syncthreads();

    // ---- KAN epilogue
    float kn0[12], kn1[12];
#pragma unroll
    for (int m = 0; m < 12; ++m) { kn0[m] = grid0[m]; kn1[m] = grid1[m]; }

    // K1: basis + silu for all 1024 (i, s) pairs
    for (int q = tid; q < 1024; q += 256) {
        const int i = q >> 4, s = q & 15;
        const float v = s_hf[s][i];
        float B[8];
        bspl8(v, kn0, B);
        *(float4*)(&s_bas[q][0]) = make_float4(B[0], B[1], B[2], B[3]);
        *(float4*)(&s_bas[q][4]) = make_float4(B[4], B[5], B[6], B[7]);
        s_bas[q][8] = v * fast_sigmoid(v);
    }
    __syncthreads();

    // K2: KAN0 out[s][o]; K3: KAN1 edge for (s,o)
    {
        const int s = tid >> 4, o = tid & 15;
        float acc = 0.0f;
        for (int i = 0; i < 64; ++i) {
            const int q = (i << 4) + s;
            const float4 B0 = *(const float4*)(&s_bas[q][0]);
            const float4 B1 = *(const float4*)(&s_bas[q][4]);
            const float sil = s_bas[q][8];
            const float* cp = coef0 + i * 128 + o * 8;
            const float4 c0 = *(const float4*)cp;
            const float4 c1 = *(const float4*)(cp + 4);
            const float spl = B0.x * c0.x + B0.y * c0.y + B0.z * c0.z + B0.w * c0.w +
                              B1.x * c1.x + B1.y * c1.y + B1.z * c1.z + B1.w * c1.w;
            acc += sil * sb0[(i << 4) + o] + sp0[(i << 4) + o] * spl;
        }
        float B[8];
        bspl8(acc, kn1, B);
        const float* cp = coef1 + o * 8;
        float spl = 0.0f;
#pragma unroll
        for (int k = 0; k < 8; ++k) spl += B[k] * cp[k];
        s_e[s][o] = (acc * fast_sigmoid(acc)) * sb1[o] + sp1[o] * spl;
    }
    __syncthreads();

    // K4: reduce 16 edges per sample, sigmoid, store
    if (tid < 16) {
        float sum = 0.0f;
#pragma unroll
        for (int o = 0; o < 16; ++o) sum += s_e[tid][o];
        out[s0 + tid] = fast_sigmoid(sum);
    }
}

extern "C" void kernel_launch(void* const* d_in, const int* in_sizes, int n_in,
                              void* d_out, int out_size, void* d_ws, size_t ws_size,
                              hipStream_t stream) {
    (void)n_in; (void)out_size; (void)d_ws; (void)ws_size;
    const int B = in_sizes[0] / (256 * 64);   // 2048
    const int grid = B / 16;                  // 128 blocks of 16 samples
    rnn_kan_v4<<<dim3(grid), dim3(256), 0, stream>>>(
        (const float*)d_in[0],
        (const float*)d_in[1], (const float*)d_in[2], (const float*)d_in[3], (const float*)d_in[4],
        (const float*)d_in[5], (const float*)d_in[6], (const float*)d_in[7], (const float*)d_in[8],
        (const float*)d_in[9], (const float*)d_in[10], (const float*)d_in[11], (const float*)d_in[12],
        (const float*)d_in[13], (const float*)d_in[14], (const float*)d_in[15], (const float*)d_in[16],
        (float*)d_out);
}